// Round 23
// baseline (104.502 us; speedup 1.0000x reference)
//
#include <hip/hip_runtime.h>
#include <hip/hip_bf16.h>
#include <stdint.h>

#define NB 8
#define DIMG 2048
#define HWN 196
#define PN 1568
#define DMID 1024
#define NC 80
#define DWORD 300
#define PART 4

typedef short bf16x8 __attribute__((ext_vector_type(8)));
typedef float f32x4 __attribute__((ext_vector_type(4)));
typedef float f32x2 __attribute__((ext_vector_type(2)));

__device__ __forceinline__ unsigned short f2bf(float x) {
  union { float f; unsigned u; } c; c.f = x;
  unsigned r = c.u + 0x7FFFu + ((c.u >> 16) & 1u);
  return (unsigned short)(r >> 16);
}

// ---------------------------------------------------------------- transpose: img -> fmap f32 [b][hw][d] + fmapH bf16; W1 cvt
__global__ void k_tc(const float* __restrict__ img, float* __restrict__ fmap,
                     unsigned short* __restrict__ fmapH,
                     const float* __restrict__ W1, unsigned short* __restrict__ W1h) {
  __shared__ float tile[64][33];
  int bx = blockIdx.x;
  int tx = threadIdx.x, ty = threadIdx.y;
  if (bx < 1792) {
    int d0 = (bx & 31) * 64;           // 32 d-tiles
    int rem = bx >> 5;                 // 0..55
    int h0 = (rem % 7) * 32, b = rem / 7;
    const float* src = img + (size_t)b * DIMG * HWN;
#pragma unroll
    for (int i = 0; i < 64; i += 8) {
      int hw = h0 + tx;
      tile[ty + i][tx] = (hw < HWN) ? src[(size_t)(d0 + ty + i) * HWN + hw] : 0.f;
    }
    __syncthreads();
#pragma unroll
    for (int i = 0; i < 32; i += 8) {
      int hw = h0 + ty + i;
      if (hw < HWN) {
        int d = tx * 2;
        float v0 = tile[d][ty + i], v1 = tile[d + 1][ty + i];
        size_t o = (size_t)(b * HWN + hw) * DIMG + d0 + d;
        f32x2 fv = {v0, v1};
        *(f32x2*)&fmap[o] = fv;
        unsigned hv = (unsigned)f2bf(v0) | ((unsigned)f2bf(v1) << 16);
        *(unsigned*)&fmapH[o] = hv;
      }
    }
  } else {
    int tid = ty * 32 + tx;
    int i = ((bx - 1792) * 256 + tid) * 4;
    f32x4 v = *(const f32x4*)(W1 + i);
    ushort4 s;
    s.x = f2bf(v[0]); s.y = f2bf(v[1]); s.z = f2bf(v[2]); s.w = f2bf(v[3]);
    *(ushort4*)(W1h + i) = s;
  }
}

// ---------------------------------------------------------------- MERGED: gemm (128^2, pipelined+swizzled, K-split-2) + fwd + weff
#define GLDS(g, l) \
  __builtin_amdgcn_global_load_lds((const __attribute__((address_space(1))) void*)(g), \
                                   (__attribute__((address_space(3))) void*)(l), 16, 0, 0)

__global__ __launch_bounds__(256) void k_gw(const unsigned short* __restrict__ A,
                                            const unsigned short* __restrict__ Bw,
                                            float* __restrict__ C,
                                            const float* __restrict__ word,
                                            const float* __restrict__ W2,
                                            float* __restrict__ fwd,
                                            const float* __restrict__ Wa,
                                            const float* __restrict__ W3,
                                            float* __restrict__ partial) {
  __shared__ __align__(16) char smem[49152];
  int bz = blockIdx.x;
  int t = threadIdx.x;
  if (bz < 208) {
    unsigned short* As = (unsigned short*)smem;
    unsigned short* Bs = As + 3 * 4096;
    int m0 = (bz % 13) * 128;
    int n0 = ((bz / 13) & 7) * 128;
    int koff = (bz / 104) * 1024;
    int w = t >> 6, l = t & 63;
    int wr = w >> 1, wc = w & 1;
    f32x4 zero = {0.f, 0.f, 0.f, 0.f};
    f32x4 acc[4][4];
#pragma unroll
    for (int i = 0; i < 4; ++i)
#pragma unroll
      for (int j = 0; j < 4; ++j) acc[i][j] = zero;

    int r0 = t >> 2, c0 = t & 3;
    int swz = (c0 ^ (r0 & 3)) << 3;
    const unsigned short* ga0 = A + (size_t)(m0 + r0) * 2048 + koff + swz;
    const unsigned short* ga1 = A + (size_t)(m0 + 64 + r0) * 2048 + koff + swz;
    const unsigned short* gb0 = Bw + (size_t)(n0 + r0) * 2048 + koff + swz;
    const unsigned short* gb1 = Bw + (size_t)(n0 + 64 + r0) * 2048 + koff + swz;

    int fr = l & 15, cc = l >> 4;
    int aswz = (cc ^ (fr & 3)) << 3;
    int a_base = (wr * 64 + fr) * 32 + aswz;
    int b_base = (wc * 64 + fr) * 32 + aswz;

#define STAGE(bi, kk) do { \
    GLDS(ga0 + (kk), As + (bi) * 4096 + t * 8); \
    GLDS(ga1 + (kk), As + (bi) * 4096 + t * 8 + 2048); \
    GLDS(gb0 + (kk), Bs + (bi) * 4096 + t * 8); \
    GLDS(gb1 + (kk), Bs + (bi) * 4096 + t * 8 + 2048); \
  } while (0)
#define COMPUTE(bi) do { \
    const unsigned short* ap = As + (bi) * 4096; \
    const unsigned short* bp = Bs + (bi) * 4096; \
    bf16x8 a[4], b[4]; \
    _Pragma("unroll") \
    for (int i = 0; i < 4; ++i) a[i] = *(const bf16x8*)&ap[a_base + i * 512]; \
    _Pragma("unroll") \
    for (int j = 0; j < 4; ++j) b[j] = *(const bf16x8*)&bp[b_base + j * 512]; \
    _Pragma("unroll") \
    for (int i = 0; i < 4; ++i) \
      _Pragma("unroll") \
      for (int j = 0; j < 4; ++j) \
        acc[i][j] = __builtin_amdgcn_mfma_f32_16x16x32_bf16(a[i], b[j], acc[i][j], 0, 0, 0); \
  } while (0)

    STAGE(0, 0);
    STAGE(1, 32);
    asm volatile("s_waitcnt vmcnt(4)" ::: "memory");
    __builtin_amdgcn_s_barrier();
    __builtin_amdgcn_sched_barrier(0);
    for (int kt = 0; kt < 32; ++kt) {
      int cur = kt % 3;
      if (kt < 30) STAGE((kt + 2) % 3, (kt + 2) * 32);
      COMPUTE(cur);
      if (kt < 30) {
        asm volatile("s_waitcnt vmcnt(4)" ::: "memory");
        __builtin_amdgcn_s_barrier();
        __builtin_amdgcn_sched_barrier(0);
      } else if (kt == 30) {
        asm volatile("s_waitcnt vmcnt(0)" ::: "memory");
        __builtin_amdgcn_s_barrier();
        __builtin_amdgcn_sched_barrier(0);
      }
    }
    float* Cz = C + (size_t)(bz / 104) * (1600 * DMID);
    int cr = (l >> 4) << 2, cc2 = l & 15;
#pragma unroll
    for (int i = 0; i < 4; ++i) {
#pragma unroll
      for (int q = 0; q < 4; ++q) {
        int row = m0 + wr * 64 + i * 16 + cr + q;
        if (row < 1600) {
#pragma unroll
          for (int j = 0; j < 4; ++j)
            Cz[(size_t)row * DMID + n0 + wc * 64 + j * 16 + cc2] = acc[i][j][q];
        }
      }
    }
#undef STAGE
#undef COMPUTE
  } else if (bz < 528) {
    float* w2s = (float*)smem;            // [16][300] 19.2 KB
    float* wds = w2s + 16 * 300;          // [16][300] 19.2 KB
    int idx = bz - 208;
    int m0 = (idx & 63) * 16, c0 = (idx >> 6) * 16;
    const float SC = 2.8853900817779268f;  // 2*log2(e)
    for (int u = t; u < 16 * 75; u += 256) {
      int r = u / 75, q = u - r * 75;
      *(f32x4*)&w2s[r * 300 + q * 4] = *(const f32x4*)(W2 + (size_t)(m0 + r) * DWORD + q * 4);
      f32x4 v = *(const f32x4*)(word + (size_t)(c0 + r) * DWORD + q * 4);
      *(f32x4*)&wds[r * 300 + q * 4] = v * SC;
    }
    __syncthreads();
    int ci = t >> 4, mi = t & 15;
    f32x4 av = {0.f, 0.f, 0.f, 0.f};
    const float* wr_ = &wds[ci * 300];
    const float* w2r = &w2s[mi * 300];
    for (int q = 0; q < 75; ++q) {
      f32x4 wv = *(const f32x4*)&wr_[q * 4];
      f32x4 bv = *(const f32x4*)&w2r[q * 4];
#pragma unroll
      for (int u = 0; u < 4; ++u) av[u] = fmaf(wv[u], bv[u], av[u]);
    }
    fwd[(size_t)(c0 + ci) * DMID + m0 + mi] = av[0] + av[1] + av[2] + av[3];
  } else {
    int idx = bz - 528;
    int m = (idx & 3) * 256 + t;
    int n0 = (idx >> 2) * 64;
    float acc = 0.f;
#pragma unroll 4
    for (int n = n0; n < n0 + 64; ++n) acc = fmaf(Wa[n], W3[(size_t)n * DMID + m], acc);
    partial[(size_t)(idx >> 2) * DMID + m] = acc;
  }
}

// ---------------------------------------------------------------- coef logits: 32p x 32c x 256m (mz=4), 2p x 2c per thread.
// LDS traffic 5 B/elem (trans-bound); MC=128 2-phase + register prefetch; grid (49,3,4).
__global__ __launch_bounds__(256) void k_coef(const float* __restrict__ fwhp,
                                              const float* __restrict__ fwd,
                                              const float* __restrict__ partial,
                                              float* __restrict__ coefp) {
  __shared__ __align__(16) float al[32][132];   // 16.9 KB
  __shared__ __align__(16) float bl[32][132];   // 16.9 KB
  __shared__ __align__(16) float wl[256];
  int p0 = blockIdx.x * 32, c0 = blockIdx.y * 32, mz = blockIdx.z;
  int mbase = mz * 256;
  int t = threadIdx.x;
  int pi = t >> 4, ci = t & 15;
  const size_t FS = (size_t)1600 * DMID;

  {  // wl[m] = -2 * sum_s partial[s][m], all 256 m
    float v = 0.f;
#pragma unroll
    for (int s = 0; s < 16; ++s) v += partial[(size_t)s * DMID + mbase + t];
    wl[t] = -2.f * v;
  }
  // stage phase 0 (coalesced): al/bl 32 rows x 128 cols, 4 f32x4 per thread each
  int sr = t >> 3, sc = (t & 7) << 4;
  const float* gA = fwhp + (size_t)(p0 + sr) * DMID + mbase + sc;
  const float* gB = fwd + (size_t)(c0 + sr) * DMID + mbase + sc;   // rows <= 95 < 96 alloc
#pragma unroll
  for (int q = 0; q < 4; ++q) {
    f32x4 v = *(const f32x4*)&gA[q * 4];
    v += *(const f32x4*)&gA[FS + q * 4];
    *(f32x4*)&al[sr][sc + q * 4] = v;
    *(f32x4*)&bl[sr][sc + q * 4] = *(const f32x4*)&gB[q * 4];
  }
  __syncthreads();

  // prefetch phase 1 into registers (hidden under phase-0 compute)
  f32x4 pa0, pa1, pa2, pa3, pb0, pb1, pb2, pb3;
  {
    const float* gA1 = gA + 128;
    const float* gB1 = gB + 128;
    pa0 = *(const f32x4*)&gA1[0]  + *(const f32x4*)&gA1[FS + 0];
    pa1 = *(const f32x4*)&gA1[4]  + *(const f32x4*)&gA1[FS + 4];
    pa2 = *(const f32x4*)&gA1[8]  + *(const f32x4*)&gA1[FS + 8];
    pa3 = *(const f32x4*)&gA1[12] + *(const f32x4*)&gA1[FS + 12];
    pb0 = *(const f32x4*)&gB1[0];
    pb1 = *(const f32x4*)&gB1[4];
    pb2 = *(const f32x4*)&gB1[8];
    pb3 = *(const f32x4*)&gB1[12];
  }

  float acc00 = 0.f, acc01 = 0.f, acc10 = 0.f, acc11 = 0.f;
#define CPHASE(woff) do { \
    for (int mm = 0; mm < 128; mm += 4) { \
      f32x4 wv = *(const f32x4*)&wl[(woff) + mm]; \
      f32x4 a0 = *(const f32x4*)&al[pi][mm]; \
      f32x4 a1 = *(const f32x4*)&al[pi + 16][mm]; \
      f32x4 b0 = *(const f32x4*)&bl[ci][mm]; \
      f32x4 b1 = *(const f32x4*)&bl[ci + 16][mm]; \
      _Pragma("unroll") \
      for (int u = 0; u < 4; ++u) { \
        float w = wv[u]; \
        float e00 = __builtin_amdgcn_exp2f(a0[u] * b0[u]); \
        float e01 = __builtin_amdgcn_exp2f(a0[u] * b1[u]); \
        float e10 = __builtin_amdgcn_exp2f(a1[u] * b0[u]); \
        float e11 = __builtin_amdgcn_exp2f(a1[u] * b1[u]); \
        acc00 = fmaf(w, __builtin_amdgcn_rcpf(1.f + e00), acc00); \
        acc01 = fmaf(w, __builtin_amdgcn_rcpf(1.f + e01), acc01); \
        acc10 = fmaf(w, __builtin_amdgcn_rcpf(1.f + e10), acc10); \
        acc11 = fmaf(w, __builtin_amdgcn_rcpf(1.f + e11), acc11); \
      } \
    } \
  } while (0)

  CPHASE(0);
  __syncthreads();
  *(f32x4*)&al[sr][sc]      = pa0;
  *(f32x4*)&al[sr][sc + 4]  = pa1;
  *(f32x4*)&al[sr][sc + 8]  = pa2;
  *(f32x4*)&al[sr][sc + 12] = pa3;
  *(f32x4*)&bl[sr][sc]      = pb0;
  *(f32x4*)&bl[sr][sc + 4]  = pb1;
  *(f32x4*)&bl[sr][sc + 8]  = pb2;
  *(f32x4*)&bl[sr][sc + 12] = pb3;
  __syncthreads();
  CPHASE(128);
#undef CPHASE

  float* cp = coefp + (size_t)mz * (PN * NC);
  int pA = p0 + pi, pB = p0 + pi + 16;
  int cA = c0 + ci, cB = c0 + ci + 16;
  if (cA < NC) {
    cp[(size_t)pA * NC + cA] = acc00;
    cp[(size_t)pB * NC + cA] = acc10;
  }
  if (cB < NC) {
    cp[(size_t)pA * NC + cB] = acc01;
    cp[(size_t)pB * NC + cB] = acc11;
  }
}

// ---------------------------------------------------------------- softmax + pooling: coalesced fmap reads, 16c tiles
__global__ __launch_bounds__(256) void k_pool(const float* __restrict__ coefp,
                                              const float* __restrict__ fmap,
                                              float* __restrict__ out) {
  __shared__ __align__(16) float wt[HWN][16];
  __shared__ float red[16][16];
  __shared__ float mxs[16], inv[16];
  int dc = blockIdx.x * 256, cg = blockIdx.y * 16, b = blockIdx.z;
  int t = threadIdx.x;
  for (int i = t; i < HWN * 4; i += 256) {
    int hw = i >> 2, j4 = (i & 3) << 2;
    size_t o = (size_t)(b * HWN + hw) * NC + cg + j4;
    f32x4 s = {0.f, 0.f, 0.f, 0.f};
#pragma unroll
    for (int z = 0; z < PART; ++z) s += *(const f32x4*)&coefp[o + (size_t)z * (PN * NC)];
    *(f32x4*)&wt[hw][j4] = s;
  }
  __syncthreads();
  int j = t & 15, g = t >> 4;
  float pm = -1e30f;
  for (int hw = g; hw < HWN; hw += 16) pm = fmaxf(pm, wt[hw][j]);
  red[g][j] = pm;
  __syncthreads();
  if (t < 16) {
    float m = red[0][t];
#pragma unroll
    for (int g2 = 1; g2 < 16; ++g2) m = fmaxf(m, red[g2][t]);
    mxs[t] = m;
  }
  __syncthreads();
  float mj = mxs[j], ps = 0.f;
  for (int hw = g; hw < HWN; hw += 16) {
    float e = __builtin_amdgcn_exp2f((wt[hw][j] - mj) * 1.4426950408889634f);
    wt[hw][j] = e;
    ps += e;
  }
  red[g][j] = ps;
  __syncthreads();
  if (t < 16) {
    float s = 0.f;
#pragma unroll
    for (int g2 = 0; g2 < 16; ++g2) s += red[g2][t];
    inv[t] = 1.f / s;
  }
  __syncthreads();
  float acc[16];
#pragma unroll
  for (int q = 0; q < 16; ++q) acc[q] = 0.f;
  const float* fp = fmap + (size_t)b * HWN * DIMG + dc + t;
  for (int h4 = 0; h4 < HWN / 4; ++h4) {
    float v0 = fp[(size_t)(h4 * 4 + 0) * DIMG];
    float v1 = fp[(size_t)(h4 * 4 + 1) * DIMG];
    float v2 = fp[(size_t)(h4 * 4 + 2) * DIMG];
    float v3 = fp[(size_t)(h4 * 4 + 3) * DIMG];
#pragma unroll
    for (int q = 0; q < 16; ++q) {
      acc[q] = fmaf(wt[h4 * 4 + 0][q], v0, acc[q]);
      acc[q] = fmaf(wt[h4 * 4 + 1][q], v1, acc[q]);
      acc[q] = fmaf(wt[h4 * 4 + 2][q], v2, acc[q]);
      acc[q] = fmaf(wt[h4 * 4 + 3][q], v3, acc[q]);
    }
  }
#pragma unroll
  for (int q = 0; q < 16; ++q)
    out[((size_t)b * NC + cg + q) * DIMG + dc + t] = acc[q] * inv[q];
}

// ----------------------------------------------------------------
extern "C" void kernel_launch(void* const* d_in, const int* in_sizes, int n_in,
                              void* d_out, int out_size, void* d_ws, size_t ws_size,
                              hipStream_t stream) {
  const float* img  = (const float*)d_in[1];
  const float* word = (const float*)d_in[2];
  const float* W1   = (const float*)d_in[3];
  const float* W2   = (const float*)d_in[4];
  const float* W3   = (const float*)d_in[5];
  const float* Wa   = (const float*)d_in[7];
  // b3 (d_in[6]) and ba (d_in[8]) are softmax-shift-invariant -> dropped.
  float* out = (float*)d_out;
  char* ws = (char*)d_ws;

  float*          fmap    = (float*)(ws + 0);                  // 1568*2048*4 = 12,845,056
  unsigned short* fmapH   = (unsigned short*)(ws + 12845056);  // 1664*2048*2 =  6,815,744
  unsigned short* W1h     = (unsigned short*)(ws + 19660800);  // 1024*2048*2 =  4,194,304
  float*          fwhp    = (float*)(ws + 23855104);           // 2*1600*1024*4 = 13,107,200
  float*          fwd     = (float*)(ws + 36962304);           //  96*1024*4 =     393,216
  float*          partial = (float*)(ws + 37355520);           //  16*1024*4 =      65,536
  float*          coefp   = (float*)(ws + 37421056);           // 4*1568*80*4 =  2,007,040

  hipLaunchKernelGGL(k_tc, dim3(3840), dim3(32, 8), 0, stream, img, fmap, fmapH, W1, W1h);
  hipLaunchKernelGGL(k_gw, dim3(592), dim3(256), 0, stream,
                     fmapH, W1h, fwhp, word, W2, fwd, Wa, W3, partial);
  hipLaunchKernelGGL(k_coef, dim3(49, 3, 4), dim3(256), 0, stream, fwhp, fwd, partial, coefp);
  hipLaunchKernelGGL(k_pool, dim3(8, 5, 8), dim3(256), 0, stream, coefp, fmap, out);
  (void)in_sizes; (void)n_in; (void)out_size; (void)ws_size;
}

// Round 24
// 91.884 us; speedup vs baseline: 1.1373x; 1.1373x over previous
//
#include <hip/hip_runtime.h>
#include <hip/hip_bf16.h>
#include <stdint.h>

#define NB 8
#define DIMG 2048
#define HWN 196
#define PN 1568
#define DMID 1024
#define NC 80
#define DWORD 300
#define PART 4

typedef short bf16x8 __attribute__((ext_vector_type(8)));
typedef float f32x4 __attribute__((ext_vector_type(4)));
typedef float f32x2 __attribute__((ext_vector_type(2)));

__device__ __forceinline__ unsigned short f2bf(float x) {
  union { float f; unsigned u; } c; c.f = x;
  unsigned r = c.u + 0x7FFFu + ((c.u >> 16) & 1u);
  return (unsigned short)(r >> 16);
}

// ---------------------------------------------------------------- transpose: img -> fmap f32 [b][hw][d] + fmapH bf16; W1 cvt
__global__ void k_tc(const float* __restrict__ img, float* __restrict__ fmap,
                     unsigned short* __restrict__ fmapH,
                     const float* __restrict__ W1, unsigned short* __restrict__ W1h) {
  __shared__ float tile[64][33];
  int bx = blockIdx.x;
  int tx = threadIdx.x, ty = threadIdx.y;
  if (bx < 1792) {
    int d0 = (bx & 31) * 64;           // 32 d-tiles
    int rem = bx >> 5;                 // 0..55
    int h0 = (rem % 7) * 32, b = rem / 7;
    const float* src = img + (size_t)b * DIMG * HWN;
#pragma unroll
    for (int i = 0; i < 64; i += 8) {
      int hw = h0 + tx;
      tile[ty + i][tx] = (hw < HWN) ? src[(size_t)(d0 + ty + i) * HWN + hw] : 0.f;
    }
    __syncthreads();
#pragma unroll
    for (int i = 0; i < 32; i += 8) {
      int hw = h0 + ty + i;
      if (hw < HWN) {
        int d = tx * 2;
        float v0 = tile[d][ty + i], v1 = tile[d + 1][ty + i];
        size_t o = (size_t)(b * HWN + hw) * DIMG + d0 + d;
        f32x2 fv = {v0, v1};
        *(f32x2*)&fmap[o] = fv;
        unsigned hv = (unsigned)f2bf(v0) | ((unsigned)f2bf(v1) << 16);
        *(unsigned*)&fmapH[o] = hv;
      }
    }
  } else {
    int tid = ty * 32 + tx;
    int i = ((bx - 1792) * 256 + tid) * 4;
    f32x4 v = *(const f32x4*)(W1 + i);
    ushort4 s;
    s.x = f2bf(v[0]); s.y = f2bf(v[1]); s.z = f2bf(v[2]); s.w = f2bf(v[3]);
    *(ushort4*)(W1h + i) = s;
  }
}

// ---------------------------------------------------------------- MERGED: gemm (128^2, pipelined+swizzled, K-split-2) + fwd + weff
#define GLDS(g, l) \
  __builtin_amdgcn_global_load_lds((const __attribute__((address_space(1))) void*)(g), \
                                   (__attribute__((address_space(3))) void*)(l), 16, 0, 0)

__global__ __launch_bounds__(256) void k_gw(const unsigned short* __restrict__ A,
                                            const unsigned short* __restrict__ Bw,
                                            float* __restrict__ C,
                                            const float* __restrict__ word,
                                            const float* __restrict__ W2,
                                            float* __restrict__ fwd,
                                            const float* __restrict__ Wa,
                                            const float* __restrict__ W3,
                                            float* __restrict__ partial) {
  __shared__ __align__(16) char smem[49152];
  int bz = blockIdx.x;
  int t = threadIdx.x;
  if (bz < 208) {
    unsigned short* As = (unsigned short*)smem;
    unsigned short* Bs = As + 3 * 4096;
    int m0 = (bz % 13) * 128;
    int n0 = ((bz / 13) & 7) * 128;
    int koff = (bz / 104) * 1024;
    int w = t >> 6, l = t & 63;
    int wr = w >> 1, wc = w & 1;
    f32x4 zero = {0.f, 0.f, 0.f, 0.f};
    f32x4 acc[4][4];
#pragma unroll
    for (int i = 0; i < 4; ++i)
#pragma unroll
      for (int j = 0; j < 4; ++j) acc[i][j] = zero;

    int r0 = t >> 2, c0 = t & 3;
    int swz = (c0 ^ (r0 & 3)) << 3;
    const unsigned short* ga0 = A + (size_t)(m0 + r0) * 2048 + koff + swz;
    const unsigned short* ga1 = A + (size_t)(m0 + 64 + r0) * 2048 + koff + swz;
    const unsigned short* gb0 = Bw + (size_t)(n0 + r0) * 2048 + koff + swz;
    const unsigned short* gb1 = Bw + (size_t)(n0 + 64 + r0) * 2048 + koff + swz;

    int fr = l & 15, cc = l >> 4;
    int aswz = (cc ^ (fr & 3)) << 3;
    int a_base = (wr * 64 + fr) * 32 + aswz;
    int b_base = (wc * 64 + fr) * 32 + aswz;

#define STAGE(bi, kk) do { \
    GLDS(ga0 + (kk), As + (bi) * 4096 + t * 8); \
    GLDS(ga1 + (kk), As + (bi) * 4096 + t * 8 + 2048); \
    GLDS(gb0 + (kk), Bs + (bi) * 4096 + t * 8); \
    GLDS(gb1 + (kk), Bs + (bi) * 4096 + t * 8 + 2048); \
  } while (0)
#define COMPUTE(bi) do { \
    const unsigned short* ap = As + (bi) * 4096; \
    const unsigned short* bp = Bs + (bi) * 4096; \
    bf16x8 a[4], b[4]; \
    _Pragma("unroll") \
    for (int i = 0; i < 4; ++i) a[i] = *(const bf16x8*)&ap[a_base + i * 512]; \
    _Pragma("unroll") \
    for (int j = 0; j < 4; ++j) b[j] = *(const bf16x8*)&bp[b_base + j * 512]; \
    _Pragma("unroll") \
    for (int i = 0; i < 4; ++i) \
      _Pragma("unroll") \
      for (int j = 0; j < 4; ++j) \
        acc[i][j] = __builtin_amdgcn_mfma_f32_16x16x32_bf16(a[i], b[j], acc[i][j], 0, 0, 0); \
  } while (0)

    STAGE(0, 0);
    STAGE(1, 32);
    asm volatile("s_waitcnt vmcnt(4)" ::: "memory");
    __builtin_amdgcn_s_barrier();
    __builtin_amdgcn_sched_barrier(0);
    for (int kt = 0; kt < 32; ++kt) {
      int cur = kt % 3;
      if (kt < 30) STAGE((kt + 2) % 3, (kt + 2) * 32);
      COMPUTE(cur);
      if (kt < 30) {
        asm volatile("s_waitcnt vmcnt(4)" ::: "memory");
        __builtin_amdgcn_s_barrier();
        __builtin_amdgcn_sched_barrier(0);
      } else if (kt == 30) {
        asm volatile("s_waitcnt vmcnt(0)" ::: "memory");
        __builtin_amdgcn_s_barrier();
        __builtin_amdgcn_sched_barrier(0);
      }
    }
    float* Cz = C + (size_t)(bz / 104) * (1600 * DMID);
    int cr = (l >> 4) << 2, cc2 = l & 15;
#pragma unroll
    for (int i = 0; i < 4; ++i) {
#pragma unroll
      for (int q = 0; q < 4; ++q) {
        int row = m0 + wr * 64 + i * 16 + cr + q;
        if (row < 1600) {
#pragma unroll
          for (int j = 0; j < 4; ++j)
            Cz[(size_t)row * DMID + n0 + wc * 64 + j * 16 + cc2] = acc[i][j][q];
        }
      }
    }
#undef STAGE
#undef COMPUTE
  } else if (bz < 528) {
    float* w2s = (float*)smem;            // [16][300] 19.2 KB
    float* wds = w2s + 16 * 300;          // [16][300] 19.2 KB
    int idx = bz - 208;
    int m0 = (idx & 63) * 16, c0 = (idx >> 6) * 16;
    const float SC = 2.8853900817779268f;  // 2*log2(e)
    for (int u = t; u < 16 * 75; u += 256) {
      int r = u / 75, q = u - r * 75;
      *(f32x4*)&w2s[r * 300 + q * 4] = *(const f32x4*)(W2 + (size_t)(m0 + r) * DWORD + q * 4);
      f32x4 v = *(const f32x4*)(word + (size_t)(c0 + r) * DWORD + q * 4);
      *(f32x4*)&wds[r * 300 + q * 4] = v * SC;
    }
    __syncthreads();
    int ci = t >> 4, mi = t & 15;
    f32x4 av = {0.f, 0.f, 0.f, 0.f};
    const float* wr_ = &wds[ci * 300];
    const float* w2r = &w2s[mi * 300];
    for (int q = 0; q < 75; ++q) {
      f32x4 wv = *(const f32x4*)&wr_[q * 4];
      f32x4 bv = *(const f32x4*)&w2r[q * 4];
#pragma unroll
      for (int u = 0; u < 4; ++u) av[u] = fmaf(wv[u], bv[u], av[u]);
    }
    fwd[(size_t)(c0 + ci) * DMID + m0 + mi] = av[0] + av[1] + av[2] + av[3];
  } else {
    int idx = bz - 528;
    int m = (idx & 3) * 256 + t;
    int n0 = (idx >> 2) * 64;
    float acc = 0.f;
#pragma unroll 4
    for (int n = n0; n < n0 + 64; ++n) acc = fmaf(Wa[n], W3[(size_t)n * DMID + m], acc);
    partial[(size_t)(idx >> 2) * DMID + m] = acc;
  }
}

// ---------------------------------------------------------------- coef logits: 32p x 16c x 256m (mz=4), sums 2 fwh K-parts
#define MC 64
__global__ __launch_bounds__(256) void k_coef(const float* __restrict__ fwhp,
                                              const float* __restrict__ fwd,
                                              const float* __restrict__ partial,
                                              float* __restrict__ coefp) {
  __shared__ __align__(16) float al[32][68];   // 8.7 KB
  __shared__ __align__(16) float bl[16][68];   // 4.3 KB
  __shared__ __align__(16) float wl[MC];
  int p0 = blockIdx.x * 32, c0 = blockIdx.y * 16, mz = blockIdx.z;
  int t = threadIdx.x;
  int pi = t >> 4, ci = t & 15;
  float acc[2] = {0.f, 0.f};
  const size_t FS = (size_t)1600 * DMID;

  for (int mc = 0; mc < 4; ++mc) {
    int mbase = mz * 256 + mc * MC;
    __syncthreads();
    {
      int sra = t >> 3, sca = (t & 7) << 3;   // al: 2 x f32x4 per thread
      const float* gA = fwhp + (size_t)(p0 + sra) * DMID + mbase + sca;
#pragma unroll
      for (int q = 0; q < 2; ++q) {
        f32x4 v = *(const f32x4*)&gA[q * 4];
        v += *(const f32x4*)&gA[FS + q * 4];
        *(f32x4*)&al[sra][sca + q * 4] = v;
      }
      int srb = t >> 4, scb = (t & 15) << 2;  // bl: 1 x f32x4 per thread
      *(f32x4*)&bl[srb][scb] = *(const f32x4*)(fwd + (size_t)(c0 + srb) * DMID + mbase + scb);
      if (t < MC) {
        float v = 0.f;
#pragma unroll
        for (int s = 0; s < 16; ++s) v += partial[(size_t)s * DMID + mbase + t];
        wl[t] = -2.f * v;
      }
    }
    __syncthreads();
    for (int mm = 0; mm < MC; mm += 4) {
      f32x4 wv = *(const f32x4*)&wl[mm];
      f32x4 bv = *(const f32x4*)&bl[ci][mm];
      f32x4 av0 = *(const f32x4*)&al[pi][mm];
      f32x4 av1 = *(const f32x4*)&al[pi + 16][mm];
#pragma unroll
      for (int u = 0; u < 4; ++u) {
        float w = wv[u], b = bv[u];
        float e0 = __builtin_amdgcn_exp2f(av0[u] * b);
        float e1 = __builtin_amdgcn_exp2f(av1[u] * b);
        acc[0] = fmaf(w, __builtin_amdgcn_rcpf(1.f + e0), acc[0]);
        acc[1] = fmaf(w, __builtin_amdgcn_rcpf(1.f + e1), acc[1]);
      }
    }
  }
  float* cp = coefp + (size_t)mz * (PN * NC);
#pragma unroll
  for (int j = 0; j < 2; ++j) {
    int p = p0 + pi + 16 * j;
    if (p < PN) cp[(size_t)p * NC + c0 + ci] = acc[j];
  }
}

// ---------------------------------------------------------------- softmax + pooling: coalesced fmap reads, 16c tiles
__global__ __launch_bounds__(256) void k_pool(const float* __restrict__ coefp,
                                              const float* __restrict__ fmap,
                                              float* __restrict__ out) {
  __shared__ __align__(16) float wt[HWN][16];
  __shared__ float red[16][16];
  __shared__ float mxs[16], inv[16];
  int dc = blockIdx.x * 256, cg = blockIdx.y * 16, b = blockIdx.z;
  int t = threadIdx.x;
  for (int i = t; i < HWN * 4; i += 256) {
    int hw = i >> 2, j4 = (i & 3) << 2;
    size_t o = (size_t)(b * HWN + hw) * NC + cg + j4;
    f32x4 s = {0.f, 0.f, 0.f, 0.f};
#pragma unroll
    for (int z = 0; z < PART; ++z) s += *(const f32x4*)&coefp[o + (size_t)z * (PN * NC)];
    *(f32x4*)&wt[hw][j4] = s;
  }
  __syncthreads();
  int j = t & 15, g = t >> 4;
  float pm = -1e30f;
  for (int hw = g; hw < HWN; hw += 16) pm = fmaxf(pm, wt[hw][j]);
  red[g][j] = pm;
  __syncthreads();
  if (t < 16) {
    float m = red[0][t];
#pragma unroll
    for (int g2 = 1; g2 < 16; ++g2) m = fmaxf(m, red[g2][t]);
    mxs[t] = m;
  }
  __syncthreads();
  float mj = mxs[j], ps = 0.f;
  for (int hw = g; hw < HWN; hw += 16) {
    float e = __builtin_amdgcn_exp2f((wt[hw][j] - mj) * 1.4426950408889634f);
    wt[hw][j] = e;
    ps += e;
  }
  red[g][j] = ps;
  __syncthreads();
  if (t < 16) {
    float s = 0.f;
#pragma unroll
    for (int g2 = 0; g2 < 16; ++g2) s += red[g2][t];
    inv[t] = 1.f / s;
  }
  __syncthreads();
  float acc[16];
#pragma unroll
  for (int q = 0; q < 16; ++q) acc[q] = 0.f;
  const float* fp = fmap + (size_t)b * HWN * DIMG + dc + t;
  for (int h4 = 0; h4 < HWN / 4; ++h4) {
    float v0 = fp[(size_t)(h4 * 4 + 0) * DIMG];
    float v1 = fp[(size_t)(h4 * 4 + 1) * DIMG];
    float v2 = fp[(size_t)(h4 * 4 + 2) * DIMG];
    float v3 = fp[(size_t)(h4 * 4 + 3) * DIMG];
#pragma unroll
    for (int q = 0; q < 16; ++q) {
      acc[q] = fmaf(wt[h4 * 4 + 0][q], v0, acc[q]);
      acc[q] = fmaf(wt[h4 * 4 + 1][q], v1, acc[q]);
      acc[q] = fmaf(wt[h4 * 4 + 2][q], v2, acc[q]);
      acc[q] = fmaf(wt[h4 * 4 + 3][q], v3, acc[q]);
    }
  }
#pragma unroll
  for (int q = 0; q < 16; ++q)
    out[((size_t)b * NC + cg + q) * DIMG + dc + t] = acc[q] * inv[q];
}

// ----------------------------------------------------------------
extern "C" void kernel_launch(void* const* d_in, const int* in_sizes, int n_in,
                              void* d_out, int out_size, void* d_ws, size_t ws_size,
                              hipStream_t stream) {
  const float* img  = (const float*)d_in[1];
  const float* word = (const float*)d_in[2];
  const float* W1   = (const float*)d_in[3];
  const float* W2   = (const float*)d_in[4];
  const float* W3   = (const float*)d_in[5];
  const float* Wa   = (const float*)d_in[7];
  // b3 (d_in[6]) and ba (d_in[8]) are softmax-shift-invariant -> dropped.
  float* out = (float*)d_out;
  char* ws = (char*)d_ws;

  float*          fmap    = (float*)(ws + 0);                  // 1568*2048*4 = 12,845,056
  unsigned short* fmapH   = (unsigned short*)(ws + 12845056);  // 1664*2048*2 =  6,815,744
  unsigned short* W1h     = (unsigned short*)(ws + 19660800);  // 1024*2048*2 =  4,194,304
  float*          fwhp    = (float*)(ws + 23855104);           // 2*1600*1024*4 = 13,107,200
  float*          fwd     = (float*)(ws + 36962304);           //  96*1024*4 =     393,216
  float*          partial = (float*)(ws + 37355520);           //  16*1024*4 =      65,536
  float*          coefp   = (float*)(ws + 37421056);           // 4*1568*80*4 =  2,007,040

  hipLaunchKernelGGL(k_tc, dim3(3840), dim3(32, 8), 0, stream, img, fmap, fmapH, W1, W1h);
  hipLaunchKernelGGL(k_gw, dim3(592), dim3(256), 0, stream,
                     fmapH, W1h, fwhp, word, W2, fwd, Wa, W3, partial);
  hipLaunchKernelGGL(k_coef, dim3(49, 5, 4), dim3(256), 0, stream, fwhp, fwd, partial, coefp);
  hipLaunchKernelGGL(k_pool, dim3(8, 5, 8), dim3(256), 0, stream, coefp, fmap, out);
  (void)in_sizes; (void)n_in; (void)out_size; (void)ws_size;
}